// Round 1
// baseline (425.279 us; speedup 1.0000x reference)
//
#include <hip/hip_runtime.h>
#include <stdint.h>

#define WAVE 64
#define CIN 64
#define COUT 64
#define KS 5

__device__ inline unsigned long long wmin64(unsigned long long v) {
#pragma unroll
  for (int o = 32; o >= 1; o >>= 1) {
    unsigned long long u = __shfl_xor(v, o, 64);
    v = (u < v) ? u : v;
  }
  return v;
}

// ---------------- SplineConv edge pass: one wave per edge ----------------
__global__ void spline_edge_kernel(const float* __restrict__ x,
                                   const int* __restrict__ ei,
                                   const float* __restrict__ pseudo,
                                   const float* __restrict__ W,
                                   float* __restrict__ acc,
                                   float* __restrict__ deg,
                                   int E_) {
  int lane = threadIdx.x & 63;
  int e = (int)((blockIdx.x * blockDim.x + threadIdx.x) >> 6);
  if (e >= E_) return;

  int src = ei[e];
  int dst = ei[E_ + e];

  float v0 = pseudo[e * 3 + 0] * (float)(KS - 1);
  float v1 = pseudo[e * 3 + 1] * (float)(KS - 1);
  float v2 = pseudo[e * 3 + 2] * (float)(KS - 1);
  float l0 = floorf(v0), l1 = floorf(v1), l2 = floorf(v2);
  float f0 = v0 - l0, f1 = v1 - l1, f2 = v2 - l2;
  int i0 = (int)l0, i1 = (int)l1, i2 = (int)l2;

  float bas[8];
  int kof[8];
#pragma unroll
  for (int s = 0; s < 8; s++) {
    int b0 = s & 1, b1 = (s >> 1) & 1, b2 = (s >> 2) & 1;
    float bb = (b0 ? f0 : 1.f - f0) * (b1 ? f1 : 1.f - f1) * (b2 ? f2 : 1.f - f2);
    int j0 = i0 + b0; j0 = j0 < 0 ? 0 : (j0 > KS - 1 ? KS - 1 : j0);
    int j1 = i1 + b1; j1 = j1 < 0 ? 0 : (j1 > KS - 1 ? KS - 1 : j1);
    int j2 = i2 + b2; j2 = j2 < 0 ? 0 : (j2 > KS - 1 ? KS - 1 : j2);
    bas[s] = bb;
    kof[s] = (j0 + KS * j1 + KS * KS * j2) * (CIN * COUT);
  }

  float xs = x[src * CIN + lane];
  float y = 0.f;
#pragma unroll 4
  for (int i = 0; i < CIN; i++) {
    float xv = __shfl(xs, i, 64);
    float t = 0.f;
#pragma unroll
    for (int s = 0; s < 8; s++) {
      t = fmaf(bas[s], W[kof[s] + (i << 6) + lane], t);
    }
    y = fmaf(xv, t, y);
  }

  atomicAdd(&acc[dst * COUT + lane], y);
  if (lane == 0) atomicAdd(&deg[dst], 1.f);
}

// ---------------- node finish: acc/deg + x@root + bias, ELU ----------------
__global__ void node_finish_kernel(const float* __restrict__ x,
                                   const float* __restrict__ root,
                                   const float* __restrict__ bias,
                                   const float* __restrict__ acc,
                                   const float* __restrict__ deg,
                                   float* __restrict__ h, int Nx_) {
  int lane = threadIdx.x & 63;
  int n = (int)((blockIdx.x * blockDim.x + threadIdx.x) >> 6);
  if (n >= Nx_) return;

  float xs = x[n * CIN + lane];
  float r = 0.f;
#pragma unroll 4
  for (int i = 0; i < CIN; i++) {
    float xv = __shfl(xs, i, 64);
    r = fmaf(xv, root[i * COUT + lane], r);
  }
  float d = deg[n];
  d = d > 1.f ? d : 1.f;
  float o = acc[n * COUT + lane] / d + r + bias[lane];
  h[n * COUT + lane] = (o > 0.f) ? o : expm1f(o);
}

// ---------------- fused kNN + inverse-distance interp: one wave per y ----------------
__global__ void knn_interp_kernel(const float* __restrict__ h,
                                  const float* __restrict__ pos_x,
                                  const float* __restrict__ pos_y,
                                  const int* __restrict__ batch_x,
                                  const int* __restrict__ batch_y,
                                  const int* __restrict__ kptr,
                                  float* __restrict__ out,
                                  int Nx_, int Ny_) {
  int lane = threadIdx.x & 63;
  int yy = (int)((blockIdx.x * blockDim.x + threadIdx.x) >> 6);
  if (yy >= Ny_) return;

  float q0 = pos_y[yy * 3 + 0], q1 = pos_y[yy * 3 + 1], q2 = pos_y[yy * 3 + 2];
  float py2 = q0 * q0 + q1 * q1 + q2 * q2;
  int by = batch_y[yy];
  int kk = *kptr;
  kk = kk < 1 ? 1 : (kk > 8 ? 8 : kk);

  unsigned long long best[8];
#pragma unroll
  for (int j = 0; j < 8; j++) best[j] = ~0ull;

  for (int t0 = 0; t0 < Nx_; t0 += 64) {
    int t = t0 + lane;
    unsigned long long key = ~0ull;
    if (t < Nx_) {
      float a0 = pos_x[t * 3 + 0], a1 = pos_x[t * 3 + 1], a2 = pos_x[t * 3 + 2];
      float px2 = a0 * a0 + a1 * a1 + a2 * a2;
      float dot = q0 * a0 + q1 * a1 + q2 * a2;
      float d2 = py2 + px2 - 2.f * dot;
      if (batch_x[t] != by) d2 = 1e10f;
      unsigned fb = __float_as_uint(d2);
      unsigned k32 = (fb & 0x80000000u) ? ~fb : (fb | 0x80000000u);
      key = (((unsigned long long)k32) << 32) | (unsigned)t;
    }
    if (key < best[7]) {
#pragma unroll
      for (int j = 0; j < 8; j++) {
        unsigned long long mn = key < best[j] ? key : best[j];
        unsigned long long mx = key < best[j] ? best[j] : key;
        best[j] = mn;
        key = mx;
      }
    }
  }

  float num = 0.f, den = 0.f;
  for (int j = 0; j < kk; j++) {
    unsigned long long m = wmin64(best[0]);
    if (best[0] == m) {
#pragma unroll
      for (int t = 0; t < 7; t++) best[t] = best[t + 1];
      best[7] = ~0ull;
    }
    unsigned u = (unsigned)(m >> 32);
    int idx = (int)(m & 0xffffffffu);
    unsigned fb = (u & 0x80000000u) ? (u & 0x7fffffffu) : ~u;
    float d2 = __uint_as_float(fb);
    float w = 1.f / fmaxf(d2, 1e-16f);
    num = fmaf(w, h[idx * COUT + lane], num);
    den += w;
  }
  out[yy * COUT + lane] = num / den;
}

extern "C" void kernel_launch(void* const* d_in, const int* in_sizes, int n_in,
                              void* d_out, int out_size, void* d_ws, size_t ws_size,
                              hipStream_t stream) {
  const float* x = (const float*)d_in[0];       // [Nx,64]
  const float* pos_x = (const float*)d_in[1];   // [Nx,3]
  const float* pos_y = (const float*)d_in[2];   // [Ny,3]
  const int* eidx = (const int*)d_in[3];        // [2,E]
  const float* pseudo = (const float*)d_in[4];  // [E,3]
  const int* batch_x = (const int*)d_in[5];     // [Nx]
  const int* batch_y = (const int*)d_in[6];     // [Ny]
  const float* W = (const float*)d_in[7];       // [125,64,64]
  const float* root = (const float*)d_in[8];    // [64,64]
  const float* bias = (const float*)d_in[9];    // [64]
  const int* kptr = (const int*)d_in[10];       // scalar k

  int Nx = in_sizes[0] / CIN;
  int Ny = in_sizes[2] / 3;
  int E = in_sizes[3] / 2;

  float* acc = (float*)d_ws;               // [Nx,64]
  float* deg = acc + (size_t)Nx * COUT;    // [Nx]
  float* h = deg + Nx;                     // [Nx,64]
  float* out = (float*)d_out;              // [Ny,64]

  // zero acc + deg (contiguous)
  hipMemsetAsync(acc, 0, ((size_t)Nx * COUT + Nx) * sizeof(float), stream);

  {
    int waves = E;
    int blocks = (waves * WAVE + 255) / 256;
    spline_edge_kernel<<<blocks, 256, 0, stream>>>(x, eidx, pseudo, W, acc, deg, E);
  }
  {
    int blocks = (Nx * WAVE + 255) / 256;
    node_finish_kernel<<<blocks, 256, 0, stream>>>(x, root, bias, acc, deg, h, Nx);
  }
  {
    int blocks = (Ny * WAVE + 255) / 256;
    knn_interp_kernel<<<blocks, 256, 0, stream>>>(h, pos_x, pos_y, batch_x, batch_y,
                                                  kptr, out, Nx, Ny);
  }
}

// Round 2
// 342.515 us; speedup vs baseline: 1.2416x; 1.2416x over previous
//
#include <hip/hip_runtime.h>
#include <stdint.h>

#define WAVE 64
#define CIN 64
#define COUT 64
#define KS 5
#define KTOT 125            // 5^3
#define KFLAT (KTOT * CIN)  // 8000
#define MT 64               // GEMM M-tile
#define KT 32               // GEMM K-step
#define NKC 10              // K-split chunks
#define KSPLIT (KFLAT / NKC)  // 800

__device__ inline unsigned long long wmin64(unsigned long long v) {
#pragma unroll
  for (int o = 32; o >= 1; o >>= 1) {
    unsigned long long u = __shfl_xor(v, o, 64);
    v = (u < v) ? u : v;
  }
  return v;
}

__device__ inline void edge_basis(const float* __restrict__ pseudo, int e,
                                  float bas[8], int kidx[8]) {
  float v0 = pseudo[e * 3 + 0] * (float)(KS - 1);
  float v1 = pseudo[e * 3 + 1] * (float)(KS - 1);
  float v2 = pseudo[e * 3 + 2] * (float)(KS - 1);
  float l0 = floorf(v0), l1 = floorf(v1), l2 = floorf(v2);
  float f0 = v0 - l0, f1 = v1 - l1, f2 = v2 - l2;
  int i0 = (int)l0, i1 = (int)l1, i2 = (int)l2;
#pragma unroll
  for (int s = 0; s < 8; s++) {
    int b0 = s & 1, b1 = (s >> 1) & 1, b2 = (s >> 2) & 1;
    float bb = (b0 ? f0 : 1.f - f0) * (b1 ? f1 : 1.f - f1) * (b2 ? f2 : 1.f - f2);
    int j0 = i0 + b0; j0 = j0 < 0 ? 0 : (j0 > KS - 1 ? KS - 1 : j0);
    int j1 = i1 + b1; j1 = j1 < 0 ? 0 : (j1 > KS - 1 ? KS - 1 : j1);
    int j2 = i2 + b2; j2 = j2 < 0 ? 0 : (j2 > KS - 1 ? KS - 1 : j2);
    bas[s] = bb;
    kidx[s] = j0 + KS * j1 + KS * KS * j2;
  }
}

// ---------- Phase 1: scatter basis-weighted x into A[dst, kidx*64 + cin] ----------
__global__ void scatter_kernel(const float* __restrict__ x,
                               const int* __restrict__ ei,
                               const float* __restrict__ pseudo,
                               float* __restrict__ A,
                               float* __restrict__ deg, int E_) {
  int lane = threadIdx.x & 63;
  int e = (int)((blockIdx.x * blockDim.x + threadIdx.x) >> 6);
  if (e >= E_) return;

  int src = ei[e];
  int dst = ei[E_ + e];
  float bas[8];
  int kidx[8];
  edge_basis(pseudo, e, bas, kidx);

  float xs = x[(size_t)src * CIN + lane];
  float* Arow = A + (size_t)dst * KFLAT + lane;
#pragma unroll
  for (int s = 0; s < 8; s++) {
    atomicAdd(Arow + kidx[s] * CIN, bas[s] * xs);
  }
  if (lane == 0) atomicAdd(&deg[dst], 1.f);
}

// ---------- Phase 2: GEMM  P[kc] = A[:, kc-slice] @ Wf[kc-slice, :] ----------
__global__ __launch_bounds__(256) void gemm_kernel(const float* __restrict__ A,
                                                   const float* __restrict__ Wf,
                                                   float* __restrict__ Pp, int Nx_) {
  __shared__ float Atr[KT][MT];    // [kk][m]
  __shared__ float Wt[KT][COUT];   // [kk][o]
  int tid = threadIdx.x;
  int row0 = blockIdx.x * MT;
  int kbase = blockIdx.y * KSPLIT;

  int mg = tid >> 4, og = tid & 15;
  int m = mg * 4, o = og * 4;
  float acc[4][4] = {};

  int r = tid >> 2;            // 0..63  (A staging row)
  int c8 = (tid & 3) * 8;      // 0,8,16,24
  int wkk = tid >> 3;          // 0..31  (W staging row)
  int wo = (tid & 7) * 8;      // 0..56

  int arow = row0 + r;
  if (arow >= Nx_) arow = Nx_ - 1;  // duplicate-read guard (stores guarded below)

  for (int k0 = kbase; k0 < kbase + KSPLIT; k0 += KT) {
    const float* wsrc = Wf + (size_t)(k0 + wkk) * COUT + wo;
    float4 w0 = *(const float4*)wsrc;
    float4 w1 = *(const float4*)(wsrc + 4);
    const float* asrc = A + (size_t)arow * KFLAT + k0 + c8;
    float4 a0 = *(const float4*)asrc;
    float4 a1 = *(const float4*)(asrc + 4);

    __syncthreads();  // previous compute done before overwrite
    *(float4*)&Wt[wkk][wo] = w0;
    *(float4*)&Wt[wkk][wo + 4] = w1;
    Atr[c8 + 0][r] = a0.x; Atr[c8 + 1][r] = a0.y;
    Atr[c8 + 2][r] = a0.z; Atr[c8 + 3][r] = a0.w;
    Atr[c8 + 4][r] = a1.x; Atr[c8 + 5][r] = a1.y;
    Atr[c8 + 6][r] = a1.z; Atr[c8 + 7][r] = a1.w;
    __syncthreads();

#pragma unroll
    for (int kk = 0; kk < KT; kk++) {
      float4 av = *(const float4*)&Atr[kk][m];
      float4 wv = *(const float4*)&Wt[kk][o];
      acc[0][0] = fmaf(av.x, wv.x, acc[0][0]);
      acc[0][1] = fmaf(av.x, wv.y, acc[0][1]);
      acc[0][2] = fmaf(av.x, wv.z, acc[0][2]);
      acc[0][3] = fmaf(av.x, wv.w, acc[0][3]);
      acc[1][0] = fmaf(av.y, wv.x, acc[1][0]);
      acc[1][1] = fmaf(av.y, wv.y, acc[1][1]);
      acc[1][2] = fmaf(av.y, wv.z, acc[1][2]);
      acc[1][3] = fmaf(av.y, wv.w, acc[1][3]);
      acc[2][0] = fmaf(av.z, wv.x, acc[2][0]);
      acc[2][1] = fmaf(av.z, wv.y, acc[2][1]);
      acc[2][2] = fmaf(av.z, wv.z, acc[2][2]);
      acc[2][3] = fmaf(av.z, wv.w, acc[2][3]);
      acc[3][0] = fmaf(av.w, wv.x, acc[3][0]);
      acc[3][1] = fmaf(av.w, wv.y, acc[3][1]);
      acc[3][2] = fmaf(av.w, wv.z, acc[3][2]);
      acc[3][3] = fmaf(av.w, wv.w, acc[3][3]);
    }
  }

  float* pbase = Pp + (size_t)blockIdx.y * Nx_ * COUT;
#pragma unroll
  for (int i = 0; i < 4; i++) {
    int rr = row0 + m + i;
    if (rr < Nx_) {
      float4 v = make_float4(acc[i][0], acc[i][1], acc[i][2], acc[i][3]);
      *(float4*)&pbase[(size_t)rr * COUT + o] = v;
    }
  }
}

// ---------- Phase 3: h = ELU(sum_k P / max(deg,1) + x@root + bias) ----------
__global__ void node_finish2_kernel(const float* __restrict__ x,
                                    const float* __restrict__ root,
                                    const float* __restrict__ bias,
                                    const float* __restrict__ Pp,
                                    const float* __restrict__ deg,
                                    float* __restrict__ h, int Nx_) {
  int lane = threadIdx.x & 63;
  int n = (int)((blockIdx.x * blockDim.x + threadIdx.x) >> 6);
  if (n >= Nx_) return;

  float s = 0.f;
#pragma unroll
  for (int kc = 0; kc < NKC; kc++) {
    s += Pp[(size_t)kc * Nx_ * COUT + (size_t)n * COUT + lane];
  }
  float xs = x[(size_t)n * CIN + lane];
  float r = 0.f;
#pragma unroll 4
  for (int i = 0; i < CIN; i++) {
    float xv = __shfl(xs, i, 64);
    r = fmaf(xv, root[i * COUT + lane], r);
  }
  float d = deg[n];
  d = d > 1.f ? d : 1.f;
  float out = s / d + r + bias[lane];
  h[(size_t)n * COUT + lane] = (out > 0.f) ? out : expm1f(out);
}

// ---------- Fallback spline (round-1 path, used only if ws too small) ----------
__global__ void spline_edge_kernel(const float* __restrict__ x,
                                   const int* __restrict__ ei,
                                   const float* __restrict__ pseudo,
                                   const float* __restrict__ W,
                                   float* __restrict__ acc,
                                   float* __restrict__ deg, int E_) {
  int lane = threadIdx.x & 63;
  int e = (int)((blockIdx.x * blockDim.x + threadIdx.x) >> 6);
  if (e >= E_) return;
  int src = ei[e];
  int dst = ei[E_ + e];
  float bas[8];
  int kidx[8];
  edge_basis(pseudo, e, bas, kidx);
  int kof[8];
#pragma unroll
  for (int s = 0; s < 8; s++) kof[s] = kidx[s] * (CIN * COUT);
  float xs = x[src * CIN + lane];
  float y = 0.f;
#pragma unroll 4
  for (int i = 0; i < CIN; i++) {
    float xv = __shfl(xs, i, 64);
    float t = 0.f;
#pragma unroll
    for (int s = 0; s < 8; s++) t = fmaf(bas[s], W[kof[s] + (i << 6) + lane], t);
    y = fmaf(xv, t, y);
  }
  atomicAdd(&acc[dst * COUT + lane], y);
  if (lane == 0) atomicAdd(&deg[dst], 1.f);
}

__global__ void node_finish_kernel(const float* __restrict__ x,
                                   const float* __restrict__ root,
                                   const float* __restrict__ bias,
                                   const float* __restrict__ acc,
                                   const float* __restrict__ deg,
                                   float* __restrict__ h, int Nx_) {
  int lane = threadIdx.x & 63;
  int n = (int)((blockIdx.x * blockDim.x + threadIdx.x) >> 6);
  if (n >= Nx_) return;
  float xs = x[n * CIN + lane];
  float r = 0.f;
#pragma unroll 4
  for (int i = 0; i < CIN; i++) {
    float xv = __shfl(xs, i, 64);
    r = fmaf(xv, root[i * COUT + lane], r);
  }
  float d = deg[n];
  d = d > 1.f ? d : 1.f;
  float o = acc[n * COUT + lane] / d + r + bias[lane];
  h[n * COUT + lane] = (o > 0.f) ? o : expm1f(o);
}

// ---------- kNN + inverse-distance interp ----------
__global__ void knn_interp_kernel(const float* __restrict__ h,
                                  const float* __restrict__ pos_x,
                                  const float* __restrict__ pos_y,
                                  const int* __restrict__ batch_x,
                                  const int* __restrict__ batch_y,
                                  const int* __restrict__ kptr,
                                  float* __restrict__ out,
                                  int Nx_, int Ny_) {
  int lane = threadIdx.x & 63;
  int yy = (int)((blockIdx.x * blockDim.x + threadIdx.x) >> 6);
  if (yy >= Ny_) return;

  float q0 = pos_y[yy * 3 + 0], q1 = pos_y[yy * 3 + 1], q2 = pos_y[yy * 3 + 2];
  float py2 = q0 * q0 + q1 * q1 + q2 * q2;
  int by = batch_y[yy];
  int kk = *kptr;
  kk = kk < 1 ? 1 : (kk > 8 ? 8 : kk);

  unsigned long long best[8];
#pragma unroll
  for (int j = 0; j < 8; j++) best[j] = ~0ull;

  for (int t0 = 0; t0 < Nx_; t0 += 64) {
    int t = t0 + lane;
    unsigned long long key = ~0ull;
    if (t < Nx_) {
      float a0 = pos_x[t * 3 + 0], a1 = pos_x[t * 3 + 1], a2 = pos_x[t * 3 + 2];
      float px2 = a0 * a0 + a1 * a1 + a2 * a2;
      float dot = q0 * a0 + q1 * a1 + q2 * a2;
      float d2 = py2 + px2 - 2.f * dot;
      if (batch_x[t] != by) d2 = 1e10f;
      unsigned fb = __float_as_uint(d2);
      unsigned k32 = (fb & 0x80000000u) ? ~fb : (fb | 0x80000000u);
      key = (((unsigned long long)k32) << 32) | (unsigned)t;
    }
    if (key < best[7]) {
#pragma unroll
      for (int j = 0; j < 8; j++) {
        unsigned long long mn = key < best[j] ? key : best[j];
        unsigned long long mx = key < best[j] ? best[j] : key;
        best[j] = mn;
        key = mx;
      }
    }
  }

  float num = 0.f, den = 0.f;
  for (int j = 0; j < kk; j++) {
    unsigned long long m = wmin64(best[0]);
    if (best[0] == m) {
#pragma unroll
      for (int t = 0; t < 7; t++) best[t] = best[t + 1];
      best[7] = ~0ull;
    }
    unsigned u = (unsigned)(m >> 32);
    int idx = (int)(m & 0xffffffffu);
    unsigned fb = (u & 0x80000000u) ? (u & 0x7fffffffu) : ~u;
    float d2 = __uint_as_float(fb);
    float w = 1.f / fmaxf(d2, 1e-16f);
    num = fmaf(w, h[(size_t)idx * COUT + lane], num);
    den += w;
  }
  out[(size_t)yy * COUT + lane] = num / den;
}

extern "C" void kernel_launch(void* const* d_in, const int* in_sizes, int n_in,
                              void* d_out, int out_size, void* d_ws, size_t ws_size,
                              hipStream_t stream) {
  const float* x = (const float*)d_in[0];
  const float* pos_x = (const float*)d_in[1];
  const float* pos_y = (const float*)d_in[2];
  const int* eidx = (const int*)d_in[3];
  const float* pseudo = (const float*)d_in[4];
  const int* batch_x = (const int*)d_in[5];
  const int* batch_y = (const int*)d_in[6];
  const float* W = (const float*)d_in[7];   // [125,64,64] == Wf[8000][64]
  const float* root = (const float*)d_in[8];
  const float* bias = (const float*)d_in[9];
  const int* kptr = (const int*)d_in[10];

  int Nx = in_sizes[0] / CIN;
  int Ny = in_sizes[2] / 3;
  int E = in_sizes[3] / 2;

  // big-path ws layout (floats): A[Nx*8000] | deg[Nx] | Pp[NKC*Nx*64] | h[Nx*64]
  size_t fA = (size_t)Nx * KFLAT;
  size_t fdeg = Nx;
  size_t fP = (size_t)NKC * Nx * COUT;
  size_t fh = (size_t)Nx * COUT;
  size_t need = (fA + fdeg + fP + fh) * sizeof(float);

  float* out = (float*)d_out;

  if (ws_size >= need) {
    float* A = (float*)d_ws;
    float* deg = A + fA;
    float* Pp = deg + fdeg;
    float* h = Pp + fP;

    hipMemsetAsync(A, 0, (fA + fdeg) * sizeof(float), stream);

    {
      int blocks = (E * WAVE + 255) / 256;
      scatter_kernel<<<blocks, 256, 0, stream>>>(x, eidx, pseudo, A, deg, E);
    }
    {
      dim3 grid((Nx + MT - 1) / MT, NKC);
      gemm_kernel<<<grid, 256, 0, stream>>>(A, W, Pp, Nx);
    }
    {
      int blocks = (Nx * WAVE + 255) / 256;
      node_finish2_kernel<<<blocks, 256, 0, stream>>>(x, root, bias, Pp, deg, h, Nx);
    }
    {
      int blocks = (Ny * WAVE + 255) / 256;
      knn_interp_kernel<<<blocks, 256, 0, stream>>>(h, pos_x, pos_y, batch_x, batch_y,
                                                    kptr, out, Nx, Ny);
    }
  } else {
    // fallback: round-1 path (small ws)
    float* acc = (float*)d_ws;
    float* deg = acc + (size_t)Nx * COUT;
    float* h = deg + Nx;
    hipMemsetAsync(acc, 0, ((size_t)Nx * COUT + Nx) * sizeof(float), stream);
    {
      int blocks = (E * WAVE + 255) / 256;
      spline_edge_kernel<<<blocks, 256, 0, stream>>>(x, eidx, pseudo, W, acc, deg, E);
    }
    {
      int blocks = (Nx * WAVE + 255) / 256;
      node_finish_kernel<<<blocks, 256, 0, stream>>>(x, root, bias, acc, deg, h, Nx);
    }
    {
      int blocks = (Ny * WAVE + 255) / 256;
      knn_interp_kernel<<<blocks, 256, 0, stream>>>(h, pos_x, pos_y, batch_x, batch_y,
                                                    kptr, out, Nx, Ny);
    }
  }
}

// Round 3
// 268.524 us; speedup vs baseline: 1.5838x; 1.2755x over previous
//
#include <hip/hip_runtime.h>
#include <stdint.h>

#define WAVE 64
#define CIN 64
#define COUT 64
#define KS 5
#define KTOT 125            // 5^3
#define KFLAT (KTOT * CIN)  // 8000
#define MT 64               // GEMM M-tile
#define KT 32               // GEMM K-step
#define NKC 10              // K-split chunks
#define KSPLIT (KFLAT / NKC)  // 800

__device__ inline unsigned long long wmin64(unsigned long long v) {
#pragma unroll
  for (int o = 32; o >= 1; o >>= 1) {
    unsigned long long u = __shfl_xor(v, o, 64);
    v = (u < v) ? u : v;
  }
  return v;
}

__device__ inline unsigned f32_orderable(float f) {
  unsigned fb = __float_as_uint(f);
  return (fb & 0x80000000u) ? ~fb : (fb | 0x80000000u);
}
__device__ inline float f32_unorderable(unsigned u) {
  unsigned fb = (u & 0x80000000u) ? (u & 0x7fffffffu) : ~u;
  return __uint_as_float(fb);
}

__device__ inline void edge_basis(const float* __restrict__ pseudo, int e,
                                  float bas[8], int kidx[8]) {
  float v0 = pseudo[e * 3 + 0] * (float)(KS - 1);
  float v1 = pseudo[e * 3 + 1] * (float)(KS - 1);
  float v2 = pseudo[e * 3 + 2] * (float)(KS - 1);
  float l0 = floorf(v0), l1 = floorf(v1), l2 = floorf(v2);
  float f0 = v0 - l0, f1 = v1 - l1, f2 = v2 - l2;
  int i0 = (int)l0, i1 = (int)l1, i2 = (int)l2;
#pragma unroll
  for (int s = 0; s < 8; s++) {
    int b0 = s & 1, b1 = (s >> 1) & 1, b2 = (s >> 2) & 1;
    float bb = (b0 ? f0 : 1.f - f0) * (b1 ? f1 : 1.f - f1) * (b2 ? f2 : 1.f - f2);
    int j0 = i0 + b0; j0 = j0 < 0 ? 0 : (j0 > KS - 1 ? KS - 1 : j0);
    int j1 = i1 + b1; j1 = j1 < 0 ? 0 : (j1 > KS - 1 ? KS - 1 : j1);
    int j2 = i2 + b2; j2 = j2 < 0 ? 0 : (j2 > KS - 1 ? KS - 1 : j2);
    bas[s] = bb;
    kidx[s] = j0 + KS * j1 + KS * KS * j2;
  }
}

// ---------- Phase 1: scatter basis-weighted x into A[dst, kidx*64 + cin] ----------
__global__ void scatter_kernel(const float* __restrict__ x,
                               const int* __restrict__ ei,
                               const float* __restrict__ pseudo,
                               float* __restrict__ A,
                               float* __restrict__ deg, int E_) {
  int lane = threadIdx.x & 63;
  int e = (int)((blockIdx.x * blockDim.x + threadIdx.x) >> 6);
  if (e >= E_) return;

  int src = ei[e];
  int dst = ei[E_ + e];
  float bas[8];
  int kidx[8];
  edge_basis(pseudo, e, bas, kidx);

  float xs = x[(size_t)src * CIN + lane];
  float* Arow = A + (size_t)dst * KFLAT + lane;
#pragma unroll
  for (int s = 0; s < 8; s++) {
    atomicAdd(Arow + kidx[s] * CIN, bas[s] * xs);
  }
  if (lane == 0) atomicAdd(&deg[dst], 1.f);
}

// ---------- Phase 2: GEMM  P[kc] = A[:, kc-slice] @ Wf[kc-slice, :] ----------
__global__ __launch_bounds__(256) void gemm_kernel(const float* __restrict__ A,
                                                   const float* __restrict__ Wf,
                                                   float* __restrict__ Pp, int Nx_) {
  __shared__ float Atr[KT][MT];    // [kk][m]
  __shared__ float Wt[KT][COUT];   // [kk][o]
  int tid = threadIdx.x;
  int row0 = blockIdx.x * MT;
  int kbase = blockIdx.y * KSPLIT;

  int mg = tid >> 4, og = tid & 15;
  int m = mg * 4, o = og * 4;
  float acc[4][4] = {};

  int r = tid >> 2;            // 0..63  (A staging row)
  int c8 = (tid & 3) * 8;      // 0,8,16,24
  int wkk = tid >> 3;          // 0..31  (W staging row)
  int wo = (tid & 7) * 8;      // 0..56

  int arow = row0 + r;
  if (arow >= Nx_) arow = Nx_ - 1;  // duplicate-read guard (stores guarded below)

  for (int k0 = kbase; k0 < kbase + KSPLIT; k0 += KT) {
    const float* wsrc = Wf + (size_t)(k0 + wkk) * COUT + wo;
    float4 w0 = *(const float4*)wsrc;
    float4 w1 = *(const float4*)(wsrc + 4);
    const float* asrc = A + (size_t)arow * KFLAT + k0 + c8;
    float4 a0 = *(const float4*)asrc;
    float4 a1 = *(const float4*)(asrc + 4);

    __syncthreads();  // previous compute done before overwrite
    *(float4*)&Wt[wkk][wo] = w0;
    *(float4*)&Wt[wkk][wo + 4] = w1;
    Atr[c8 + 0][r] = a0.x; Atr[c8 + 1][r] = a0.y;
    Atr[c8 + 2][r] = a0.z; Atr[c8 + 3][r] = a0.w;
    Atr[c8 + 4][r] = a1.x; Atr[c8 + 5][r] = a1.y;
    Atr[c8 + 6][r] = a1.z; Atr[c8 + 7][r] = a1.w;
    __syncthreads();

#pragma unroll
    for (int kk = 0; kk < KT; kk++) {
      float4 av = *(const float4*)&Atr[kk][m];
      float4 wv = *(const float4*)&Wt[kk][o];
      acc[0][0] = fmaf(av.x, wv.x, acc[0][0]);
      acc[0][1] = fmaf(av.x, wv.y, acc[0][1]);
      acc[0][2] = fmaf(av.x, wv.z, acc[0][2]);
      acc[0][3] = fmaf(av.x, wv.w, acc[0][3]);
      acc[1][0] = fmaf(av.y, wv.x, acc[1][0]);
      acc[1][1] = fmaf(av.y, wv.y, acc[1][1]);
      acc[1][2] = fmaf(av.y, wv.z, acc[1][2]);
      acc[1][3] = fmaf(av.y, wv.w, acc[1][3]);
      acc[2][0] = fmaf(av.z, wv.x, acc[2][0]);
      acc[2][1] = fmaf(av.z, wv.y, acc[2][1]);
      acc[2][2] = fmaf(av.z, wv.z, acc[2][2]);
      acc[2][3] = fmaf(av.z, wv.w, acc[2][3]);
      acc[3][0] = fmaf(av.w, wv.x, acc[3][0]);
      acc[3][1] = fmaf(av.w, wv.y, acc[3][1]);
      acc[3][2] = fmaf(av.w, wv.z, acc[3][2]);
      acc[3][3] = fmaf(av.w, wv.w, acc[3][3]);
    }
  }

  float* pbase = Pp + (size_t)blockIdx.y * Nx_ * COUT;
#pragma unroll
  for (int i = 0; i < 4; i++) {
    int rr = row0 + m + i;
    if (rr < Nx_) {
      float4 v = make_float4(acc[i][0], acc[i][1], acc[i][2], acc[i][3]);
      *(float4*)&pbase[(size_t)rr * COUT + o] = v;
    }
  }
}

// ---------- Phase 3: h = ELU(sum_k P / max(deg,1) + x@root + bias) ----------
__global__ void node_finish2_kernel(const float* __restrict__ x,
                                    const float* __restrict__ root,
                                    const float* __restrict__ bias,
                                    const float* __restrict__ Pp,
                                    const float* __restrict__ deg,
                                    float* __restrict__ h, int Nx_) {
  int lane = threadIdx.x & 63;
  int n = (int)((blockIdx.x * blockDim.x + threadIdx.x) >> 6);
  if (n >= Nx_) return;

  float s = 0.f;
#pragma unroll
  for (int kc = 0; kc < NKC; kc++) {
    s += Pp[(size_t)kc * Nx_ * COUT + (size_t)n * COUT + lane];
  }
  float xs = x[(size_t)n * CIN + lane];
  float r = 0.f;
#pragma unroll 4
  for (int i = 0; i < CIN; i++) {
    float xv = __shfl(xs, i, 64);
    r = fmaf(xv, root[i * COUT + lane], r);
  }
  float d = deg[n];
  d = d > 1.f ? d : 1.f;
  float out = s / d + r + bias[lane];
  h[(size_t)n * COUT + lane] = (out > 0.f) ? out : expm1f(out);
}

// ---------- Fallback spline (round-1 path, used only if ws too small) ----------
__global__ void spline_edge_kernel(const float* __restrict__ x,
                                   const int* __restrict__ ei,
                                   const float* __restrict__ pseudo,
                                   const float* __restrict__ W,
                                   float* __restrict__ acc,
                                   float* __restrict__ deg, int E_) {
  int lane = threadIdx.x & 63;
  int e = (int)((blockIdx.x * blockDim.x + threadIdx.x) >> 6);
  if (e >= E_) return;
  int src = ei[e];
  int dst = ei[E_ + e];
  float bas[8];
  int kidx[8];
  edge_basis(pseudo, e, bas, kidx);
  int kof[8];
#pragma unroll
  for (int s = 0; s < 8; s++) kof[s] = kidx[s] * (CIN * COUT);
  float xs = x[src * CIN + lane];
  float y = 0.f;
#pragma unroll 4
  for (int i = 0; i < CIN; i++) {
    float xv = __shfl(xs, i, 64);
    float t = 0.f;
#pragma unroll
    for (int s = 0; s < 8; s++) t = fmaf(bas[s], W[kof[s] + (i << 6) + lane], t);
    y = fmaf(xv, t, y);
  }
  atomicAdd(&acc[dst * COUT + lane], y);
  if (lane == 0) atomicAdd(&deg[dst], 1.f);
}

__global__ void node_finish_kernel(const float* __restrict__ x,
                                   const float* __restrict__ root,
                                   const float* __restrict__ bias,
                                   const float* __restrict__ acc,
                                   const float* __restrict__ deg,
                                   float* __restrict__ h, int Nx_) {
  int lane = threadIdx.x & 63;
  int n = (int)((blockIdx.x * blockDim.x + threadIdx.x) >> 6);
  if (n >= Nx_) return;
  float xs = x[n * CIN + lane];
  float r = 0.f;
#pragma unroll 4
  for (int i = 0; i < CIN; i++) {
    float xv = __shfl(xs, i, 64);
    r = fmaf(xv, root[i * COUT + lane], r);
  }
  float d = deg[n];
  d = d > 1.f ? d : 1.f;
  float o = acc[n * COUT + lane] / d + r + bias[lane];
  h[n * COUT + lane] = (o > 0.f) ? o : expm1f(o);
}

// ---------- kNN pre-pack: [x0,x1,x2,|x|^2] per candidate ----------
__global__ void pack_posx_kernel(const float* __restrict__ pos_x,
                                 float4* __restrict__ pxp, int Nx_) {
  int t = blockIdx.x * blockDim.x + threadIdx.x;
  if (t >= Nx_) return;
  float a0 = pos_x[t * 3 + 0], a1 = pos_x[t * 3 + 1], a2 = pos_x[t * 3 + 2];
  pxp[t] = make_float4(a0, a1, a2, a0 * a0 + a1 * a1 + a2 * a2);
}

// ---------- fused kNN + inverse-distance interp (k-specialized) ----------
__global__ void knn_interp2_kernel(const float* __restrict__ h,
                                   const float4* __restrict__ pxp,
                                   const float* __restrict__ pos_y,
                                   const int* __restrict__ batch_x,
                                   const int* __restrict__ batch_y,
                                   const int* __restrict__ kptr,
                                   float* __restrict__ out,
                                   int Nx_, int Ny_) {
  int lane = threadIdx.x & 63;
  int yy = (int)((blockIdx.x * blockDim.x + threadIdx.x) >> 6);
  if (yy >= Ny_) return;

  float q0 = pos_y[yy * 3 + 0], q1 = pos_y[yy * 3 + 1], q2 = pos_y[yy * 3 + 2];
  float py2 = q0 * q0 + q1 * q1 + q2 * q2;
  int by = batch_y[yy];
  int kk = *kptr;
  kk = kk < 1 ? 1 : (kk > 8 ? 8 : kk);

  float num = 0.f, den = 0.f;

  if (kk <= 3) {
    const float FINF = __uint_as_float(0x7f800000u);
    float bd0 = FINF, bd1 = FINF, bd2 = FINF;
    unsigned bi0 = ~0u, bi1 = ~0u, bi2 = ~0u;

    for (int t0 = 0; t0 < Nx_; t0 += 64) {
      int t = t0 + lane;
      int tc = t < Nx_ ? t : Nx_ - 1;
      float4 p = pxp[tc];
      float dot = fmaf(q0, p.x, fmaf(q1, p.y, q2 * p.z));
      float d2 = fmaf(-2.f, dot, py2 + p.w);
      if (batch_x[tc] != by) d2 = 1e10f;
      if (t >= Nx_) d2 = FINF;

      float kv = d2;
      unsigned ki = (unsigned)t;
      // unconditional 3-stage insertion (strict < keeps earlier index on ties)
      {
        bool lt = kv < bd0;
        float nv = lt ? kv : bd0; float xv = lt ? bd0 : kv;
        unsigned ni = lt ? ki : bi0; unsigned xi = lt ? bi0 : ki;
        bd0 = nv; bi0 = ni; kv = xv; ki = xi;
      }
      {
        bool lt = kv < bd1;
        float nv = lt ? kv : bd1; float xv = lt ? bd1 : kv;
        unsigned ni = lt ? ki : bi1; unsigned xi = lt ? bi1 : ki;
        bd1 = nv; bi1 = ni; kv = xv; ki = xi;
      }
      {
        bool lt = kv < bd2;
        float nv = lt ? kv : bd2;
        unsigned ni = lt ? ki : bi2;
        bd2 = nv; bi2 = ni;
      }
    }

    unsigned long long c0 = (((unsigned long long)f32_orderable(bd0)) << 32) | bi0;
    unsigned long long c1 = (((unsigned long long)f32_orderable(bd1)) << 32) | bi1;
    unsigned long long c2 = (((unsigned long long)f32_orderable(bd2)) << 32) | bi2;

    for (int j = 0; j < kk; j++) {
      unsigned long long m = wmin64(c0);
      if (c0 == m) { c0 = c1; c1 = c2; c2 = ~0ull; }
      unsigned u = (unsigned)(m >> 32);
      int idx = (int)(m & 0xffffffffu);
      idx = (idx < 0 || idx >= Nx_) ? 0 : idx;
      float d2 = f32_unorderable(u);
      float w = 1.f / fmaxf(d2, 1e-16f);
      num = fmaf(w, h[(size_t)idx * COUT + lane], num);
      den += w;
    }
  } else {
    unsigned long long best[8];
#pragma unroll
    for (int j = 0; j < 8; j++) best[j] = ~0ull;

    for (int t0 = 0; t0 < Nx_; t0 += 64) {
      int t = t0 + lane;
      unsigned long long key = ~0ull;
      if (t < Nx_) {
        float4 p = pxp[t];
        float dot = fmaf(q0, p.x, fmaf(q1, p.y, q2 * p.z));
        float d2 = fmaf(-2.f, dot, py2 + p.w);
        if (batch_x[t] != by) d2 = 1e10f;
        key = (((unsigned long long)f32_orderable(d2)) << 32) | (unsigned)t;
      }
      if (key < best[7]) {
#pragma unroll
        for (int j = 0; j < 8; j++) {
          unsigned long long mn = key < best[j] ? key : best[j];
          unsigned long long mx = key < best[j] ? best[j] : key;
          best[j] = mn;
          key = mx;
        }
      }
    }

    for (int j = 0; j < kk; j++) {
      unsigned long long m = wmin64(best[0]);
      if (best[0] == m) {
#pragma unroll
        for (int t = 0; t < 7; t++) best[t] = best[t + 1];
        best[7] = ~0ull;
      }
      unsigned u = (unsigned)(m >> 32);
      int idx = (int)(m & 0xffffffffu);
      idx = (idx < 0 || idx >= Nx_) ? 0 : idx;
      float d2 = f32_unorderable(u);
      float w = 1.f / fmaxf(d2, 1e-16f);
      num = fmaf(w, h[(size_t)idx * COUT + lane], num);
      den += w;
    }
  }

  out[(size_t)yy * COUT + lane] = num / den;
}

extern "C" void kernel_launch(void* const* d_in, const int* in_sizes, int n_in,
                              void* d_out, int out_size, void* d_ws, size_t ws_size,
                              hipStream_t stream) {
  const float* x = (const float*)d_in[0];
  const float* pos_x = (const float*)d_in[1];
  const float* pos_y = (const float*)d_in[2];
  const int* eidx = (const int*)d_in[3];
  const float* pseudo = (const float*)d_in[4];
  const int* batch_x = (const int*)d_in[5];
  const int* batch_y = (const int*)d_in[6];
  const float* W = (const float*)d_in[7];   // [125,64,64] == Wf[8000][64]
  const float* root = (const float*)d_in[8];
  const float* bias = (const float*)d_in[9];
  const int* kptr = (const int*)d_in[10];

  int Nx = in_sizes[0] / CIN;
  int Ny = in_sizes[2] / 3;
  int E = in_sizes[3] / 2;

  // big-path ws layout (floats): A | deg | Pp | h | pxp
  size_t fA = (size_t)Nx * KFLAT;
  size_t fdeg = Nx;
  size_t fP = (size_t)NKC * Nx * COUT;
  size_t fh = (size_t)Nx * COUT;
  size_t fpx = (size_t)Nx * 4;
  size_t need = (fA + fdeg + fP + fh + fpx) * sizeof(float);

  float* out = (float*)d_out;

  if (ws_size >= need) {
    float* A = (float*)d_ws;
    float* deg = A + fA;
    float* Pp = deg + fdeg;
    float* h = Pp + fP;
    float4* pxp = (float4*)(h + fh);

    hipMemsetAsync(A, 0, (fA + fdeg) * sizeof(float), stream);

    {
      int blocks = (E * WAVE + 255) / 256;
      scatter_kernel<<<blocks, 256, 0, stream>>>(x, eidx, pseudo, A, deg, E);
    }
    {
      dim3 grid((Nx + MT - 1) / MT, NKC);
      gemm_kernel<<<grid, 256, 0, stream>>>(A, W, Pp, Nx);
    }
    {
      int blocks = (Nx * WAVE + 255) / 256;
      node_finish2_kernel<<<blocks, 256, 0, stream>>>(x, root, bias, Pp, deg, h, Nx);
    }
    pack_posx_kernel<<<(Nx + 255) / 256, 256, 0, stream>>>(pos_x, pxp, Nx);
    {
      int blocks = (Ny * WAVE + 255) / 256;
      knn_interp2_kernel<<<blocks, 256, 0, stream>>>(h, pxp, pos_y, batch_x, batch_y,
                                                     kptr, out, Nx, Ny);
    }
  } else {
    // fallback: round-1 path (small ws)
    float* acc = (float*)d_ws;
    float* deg = acc + (size_t)Nx * COUT;
    float* h = deg + Nx;
    float4* pxp = (float4*)(h + (size_t)Nx * COUT);
    hipMemsetAsync(acc, 0, ((size_t)Nx * COUT + Nx) * sizeof(float), stream);
    {
      int blocks = (E * WAVE + 255) / 256;
      spline_edge_kernel<<<blocks, 256, 0, stream>>>(x, eidx, pseudo, W, acc, deg, E);
    }
    {
      int blocks = (Nx * WAVE + 255) / 256;
      node_finish_kernel<<<blocks, 256, 0, stream>>>(x, root, bias, acc, deg, h, Nx);
    }
    pack_posx_kernel<<<(Nx + 255) / 256, 256, 0, stream>>>(pos_x, pxp, Nx);
    {
      int blocks = (Ny * WAVE + 255) / 256;
      knn_interp2_kernel<<<blocks, 256, 0, stream>>>(h, pxp, pos_y, batch_x, batch_y,
                                                     kptr, out, Nx, Ny);
    }
  }
}